// Round 12
// baseline (612.615 us; speedup 1.0000x reference)
//
#include <hip/hip_runtime.h>
#include <hip/hip_bf16.h>
#include <stdint.h>

#define T_TOK 2048
#define HD    2048
#define NE    16
#define FF    1024
#define TOPK  4
#define SHF   5632

typedef __attribute__((ext_vector_type(8))) short short8;
typedef __attribute__((ext_vector_type(4))) float f32x4;

typedef const __attribute__((address_space(1))) uint32_t* gp1_t;
typedef __attribute__((address_space(3))) uint32_t* lp3_t;

__device__ __forceinline__ void gload_lds16(const void* g, void* l) {
  __builtin_amdgcn_global_load_lds((gp1_t)g, (lp3_t)l, 16, 0, 0);
}

__device__ __forceinline__ unsigned short f2bf(float f) {
  __hip_bfloat16 h = __float2bfloat16(f);
  return __builtin_bit_cast(unsigned short, h);
}
__device__ __forceinline__ float bf2f(unsigned short u) {
  return __uint_as_float(((uint32_t)u) << 16);
}

// ---------------- prep: x -> bf16 ----------------------------------------------
__global__ __launch_bounds__(256) void k_prep(const float* __restrict__ x,
                                              unsigned short* __restrict__ xb, int n) {
  int i = blockIdx.x * blockDim.x + threadIdx.x;
  int stride = gridDim.x * blockDim.x;
  for (; i < n; i += stride) xb[i] = f2bf(x[i]);
}

// ---------------- weight transpose+cast: [b][K][N] fp32 -> [b][N][K] bf16 ------
// (only used for the two down-projection weights now)
__global__ __launch_bounds__(256) void k_transpose(const float* __restrict__ src,
    unsigned short* __restrict__ dst, int K, int N) {
  __shared__ unsigned short tile[64][72];
  const int k0 = blockIdx.x * 64;
  const int n0 = blockIdx.y * 64;
  const size_t boff = (size_t)blockIdx.z * K * N;
  src += boff; dst += boff;
  const int t = threadIdx.x;
  const int c4 = (t & 15) * 4;
  const int kr0 = (t >> 4) * 4;
#pragma unroll
  for (int j = 0; j < 4; ++j) {
    int kr = kr0 + j;
    float4 v = *(const float4*)(src + (size_t)(k0 + kr) * N + n0 + c4);
    tile[c4 + 0][kr] = f2bf(v.x);
    tile[c4 + 1][kr] = f2bf(v.y);
    tile[c4 + 2][kr] = f2bf(v.z);
    tile[c4 + 3][kr] = f2bf(v.w);
  }
  __syncthreads();
  const int nr = t >> 2;
  const int kc = (t & 3) * 8;
  unsigned short* orow = dst + (size_t)(n0 + nr) * K + k0;
  *(short8*)(orow + kc)      = *(const short8*)(&tile[nr][kc]);
  *(short8*)(orow + kc + 32) = *(const short8*)(&tile[nr][kc + 32]);
}

// ---------------- router: wave = token, float4 loads, NO atomics ---------------
__global__ __launch_bounds__(256) void k_router2(
    const float* __restrict__ x, const float* __restrict__ wr,
    const float* __restrict__ wsg,
    int* __restrict__ tk_ids, float* __restrict__ tk_w,
    float* __restrict__ gate_sh) {
  const int t = blockIdx.x * 4 + (threadIdx.x >> 6);
  const int lane = threadIdx.x & 63;
  const float4* x4  = (const float4*)(x + (size_t)t * HD);
  const float4* wg4 = (const float4*)wsg;
  float p[NE + 1];
#pragma unroll
  for (int e = 0; e <= NE; ++e) p[e] = 0.f;
#pragma unroll
  for (int j = 0; j < 8; ++j) {
    const int i4 = lane + 64 * j;
    float4 xv = x4[i4];
    const float4* wrow = (const float4*)(wr + (size_t)i4 * 4 * NE);
#pragma unroll
    for (int r = 0; r < 4; ++r) {
      float xs = (&xv.x)[r];
#pragma unroll
      for (int c = 0; c < 4; ++c) {
        float4 wv = wrow[r * 4 + c];
        p[c * 4 + 0] += xs * wv.x;
        p[c * 4 + 1] += xs * wv.y;
        p[c * 4 + 2] += xs * wv.z;
        p[c * 4 + 3] += xs * wv.w;
      }
    }
    float4 gv = wg4[i4];
    p[NE] += xv.x * gv.x + xv.y * gv.y + xv.z * gv.z + xv.w * gv.w;
  }
#pragma unroll
  for (int e = 0; e <= NE; ++e) {
    float v = p[e];
    for (int off = 32; off; off >>= 1) v += __shfl_xor(v, off);
    p[e] = v;
  }
  if (lane == 0) {
    gate_sh[t] = 1.f / (1.f + __expf(-p[NE]));
    float l[NE];
#pragma unroll
    for (int e = 0; e < NE; ++e) l[e] = p[e];
    int ids[TOPK]; float lg[TOPK];
#pragma unroll
    for (int k = 0; k < TOPK; ++k) {
      int best = 0; float bv = l[0];
#pragma unroll
      for (int e = 1; e < NE; ++e) { if (l[e] > bv) { bv = l[e]; best = e; } }
      ids[k] = best; lg[k] = bv; l[best] = -1e30f;
    }
    float m = lg[0], s = 0.f, w[TOPK];
#pragma unroll
    for (int k = 0; k < TOPK; ++k) { w[k] = __expf(lg[k] - m); s += w[k]; }
    float inv = 1.f / s;
#pragma unroll
    for (int k = 0; k < TOPK; ++k) {
      tk_ids[t * TOPK + k] = ids[k];
      tk_w[t * TOPK + k] = w[k] * inv;
    }
  }
}

// ---------------- counts + offsets via LDS histogram (1 block) -----------------
__global__ __launch_bounds__(256) void k_offsets2(
    const int* __restrict__ tk_ids, int* __restrict__ counts,
    int* __restrict__ offsets) {
  __shared__ int h[NE];
  const int tid = threadIdx.x;
  if (tid < NE) h[tid] = 0;
  __syncthreads();
  for (int i = tid; i < T_TOK * TOPK; i += 256) atomicAdd(&h[tk_ids[i]], 1);
  __syncthreads();
  if (tid == 0) {
    int off = 0;
    for (int e = 0; e < NE; ++e) { counts[e] = h[e]; offsets[e] = off; off += h[e]; }
    offsets[NE] = off;
  }
}

// ---------------- per-expert list build: ballot prefix, token-ordered ----------
__global__ __launch_bounds__(256) void k_build(
    const int* __restrict__ tk_ids, const float* __restrict__ tk_w,
    const int* __restrict__ offsets, int* __restrict__ list,
    float* __restrict__ wpair) {
  const int e = blockIdx.x;
  const int tid = threadIdx.x, lane = tid & 63, w = tid >> 6;
  __shared__ int wbase[4];
  __shared__ int sbase;
  if (tid == 0) sbase = 0;
  __syncthreads();
  const int obase = offsets[e];
  for (int c = 0; c < T_TOK / 256; ++c) {
    int t = c * 256 + tid;
    int m = -1;
#pragma unroll
    for (int k = 0; k < TOPK; ++k)
      if (tk_ids[t * TOPK + k] == e) m = k;
    unsigned long long mask = __ballot(m >= 0);
    int posw = __popcll(mask & ((1ull << lane) - 1ull));
    if (lane == 0) wbase[w] = __popcll(mask);
    __syncthreads();
    int wb = 0;
#pragma unroll
    for (int j = 0; j < 4; ++j) if (j < w) wb += wbase[j];
    int tot = wbase[0] + wbase[1] + wbase[2] + wbase[3];
    if (m >= 0) {
      int pos = sbase + wb + posw;
      list[e * T_TOK + pos] = t;
      wpair[obase + pos] = tk_w[t * TOPK + m];
    }
    __syncthreads();
    if (tid == 0) sbase += tot;
    __syncthreads();
  }
}

// ---------------- 128x128x64 bf16 MFMA GEMM, mixed-core -----------------------
// MODE 0/2 (combined g+u, K=2048): sync core, 33 KB LDS, 4 blocks/CU; B read
//   DIRECTLY from fp32 [K][N] weights: coalesced float4 row loads -> register
//   4x4 transpose -> bf16 -> ds_write_b64 into swizzled [n][k] LDS tile.
//   B swizzle ((n&7)^((n>>2)&7))<<4: reads 2-way (free), writes 4-way.
// MODE 1/3 (down projections): dbuf 2-phase core, 66 KB LDS, counted vmcnt(8),
//   B = pre-transposed bf16 via gload_lds (unchanged).
template<int MODE>
__global__ __launch_bounds__(256) void k_gemm(
    const unsigned short* __restrict__ A, int lda, int K,
    const unsigned short* __restrict__ B0, const unsigned short* __restrict__ B1,
    const float* __restrict__ BF0, const float* __restrict__ BF1, int ldbn,
    int nsplit, size_t strideB,
    unsigned short* __restrict__ O0, unsigned short* __restrict__ O1, int ldo,
    float* __restrict__ OF,
    const int* __restrict__ counts, const int* __restrict__ offsets,
    const int* __restrict__ list, const float* __restrict__ gate_sh)
{
  constexpr bool DBUF = (MODE == 1 || MODE == 3);
  __shared__ unsigned short lds[DBUF ? 2 * 16384 : 16384];
  __shared__ int tokLDS[128];

  const int cb = blockIdx.x, rb = blockIdx.y;
  const int e = (MODE <= 1) ? blockIdx.z : 0;
  const int tid = threadIdx.x, l = tid & 63, wid = tid >> 6;
  const int wr = wid >> 1, wc = wid & 1;

  int cnt = T_TOK;
  if (MODE <= 1) {
    cnt = counts[e];
    if (rb * 128 >= cnt) return;
  }
  if (MODE == 0) {
    if (tid < 128) {
      int r = rb * 128 + tid;
      tokLDS[tid] = list[e * T_TOK + (r < cnt ? r : cnt - 1)];
    }
    __syncthreads();
  }

  const int swz8 = ((l & 7) ^ (l >> 3)) * 8;
  const int cb2 = (cb < nsplit) ? cb : cb - nsplit;

  const unsigned short* aS[4];
  const unsigned short* bS[4];
#pragma unroll
  for (int i = 0; i < 4; ++i) {
    int rloc = wid * 32 + i * 8 + (l >> 3);
    int arow;
    if (MODE == 0) arow = tokLDS[rloc];
    else if (MODE == 1) { int rr = rb * 128 + rloc; if (rr >= cnt) rr = cnt - 1; arow = offsets[e] + rr; }
    else arow = rb * 128 + rloc;
    aS[i] = A + (size_t)arow * lda + swz8;
    if (DBUF) {
      const unsigned short* Bsel = (cb < nsplit) ? B0 : B1;
      const size_t eoff = (MODE == 1) ? (size_t)e * strideB : (size_t)0;
      bS[i] = Bsel + eoff + (size_t)(cb2 * 128 + rloc) * K + swz8;
    }
  }

  // fp32 B base for MODE 0/2: row-coalesced float4 loads
  const float* bFp = nullptr;
  const int bn0 = (tid & 31) * 4;   // n within tile (0..124)
  const int bk0 = (tid >> 5) * 4;   // k quad base  (0..28)
  if (!DBUF) {
    const float* Bsel = (cb < nsplit) ? BF0 : BF1;
    const size_t eoff = (MODE == 0) ? (size_t)e * strideB : (size_t)0;
    bFp = Bsel + eoff + cb2 * 128 + bn0;
  }

  f32x4 acc[4][4];
#pragma unroll
  for (int mf = 0; mf < 4; ++mf)
#pragma unroll
    for (int nf = 0; nf < 4; ++nf) acc[mf][nf] = (f32x4){0.f, 0.f, 0.f, 0.f};

  const int nkt = K / 64;

  if constexpr (!DBUF) {
    // ---- sync core with fused fp32->bf16 transposing B staging ----
    for (int kt = 0; kt < nkt; ++kt) {
      const int k0 = kt * 64;
      unsigned short* baseA = &lds[0] + (wid * 32) * 64;
#pragma unroll
      for (int i = 0; i < 4; ++i)
        gload_lds16(aS[i] + k0, baseA + i * 8 * 64);

      // load 2 x (4x4 fp32 block), coalesced rows
      float4 v[2][4];
#pragma unroll
      for (int b = 0; b < 2; ++b)
#pragma unroll
        for (int j = 0; j < 4; ++j)
          v[b][j] = *(const float4*)(bFp + (size_t)(k0 + bk0 + b * 32 + j) * ldbn);
      // register transpose + cvt + ds_write_b64 into swizzled [n][k]
      char* lBc = (char*)(&lds[0]) + 16384;
#pragma unroll
      for (int b = 0; b < 2; ++b) {
        const int kq = bk0 + b * 32;
        const int chunk = (kq >> 3) << 4;
        const int sub = (kq & 7) * 2;
#pragma unroll
        for (int c = 0; c < 4; ++c) {
          const int n = bn0 + c;
          uint32_t lo = (uint32_t)f2bf((&v[b][0].x)[c]) | ((uint32_t)f2bf((&v[b][1].x)[c]) << 16);
          uint32_t hi = (uint32_t)f2bf((&v[b][2].x)[c]) | ((uint32_t)f2bf((&v[b][3].x)[c]) << 16);
          const int swzB = ((n & 7) ^ ((n >> 2) & 7)) << 4;
          *(uint2*)(lBc + n * 128 + (chunk ^ swzB) + sub) = make_uint2(lo, hi);
        }
      }
      __syncthreads();
      const char* lAb = (const char*)&lds[0];
      const char* lBb = lAb + 16384;
#pragma unroll
      for (int kk = 0; kk < 2; ++kk) {
        const int kb = kk * 64 + ((l >> 4) * 16);
        short8 af[4], bf[4];
#pragma unroll
        for (int mf = 0; mf < 4; ++mf) {
          int row = wr * 64 + mf * 16 + (l & 15);
          af[mf] = *(const short8*)(lAb + row * 128 + (kb ^ ((row & 7) << 4)));
        }
#pragma unroll
        for (int nf = 0; nf < 4; ++nf) {
          int n = wc * 64 + nf * 16 + (l & 15);
          const int swzB = ((n & 7) ^ ((n >> 2) & 7)) << 4;
          bf[nf] = *(const short8*)(lBb + n * 128 + (kb ^ swzB));
        }
#pragma unroll
        for (int mf = 0; mf < 4; ++mf)
#pragma unroll
          for (int nf = 0; nf < 4; ++nf)
            acc[mf][nf] = __builtin_amdgcn_mfma_f32_16x16x32_bf16(af[mf], bf[nf], acc[mf][nf], 0, 0, 0);
      }
      __syncthreads();
    }
  } else {
    // ---- dbuf 2-phase core (best for short-K down gemms) ----
    auto STAGE = [&](int kt) {
      unsigned short* base = &lds[0] + (kt & 1) * 16384 + (wid * 32) * 64;
      const int k0 = kt * 64;
#pragma unroll
      for (int i = 0; i < 4; ++i) {
        gload_lds16(aS[i] + k0, base + i * 8 * 64);
        gload_lds16(bS[i] + k0, base + i * 8 * 64 + 8192);
      }
    };
    STAGE(0);
    for (int kt = 0; kt < nkt; ++kt) {
      if (kt + 1 < nkt) {
        STAGE(kt + 1);
        asm volatile("s_waitcnt vmcnt(8)" ::: "memory");
      } else {
        asm volatile("s_waitcnt vmcnt(0)" ::: "memory");
      }
      __builtin_amdgcn_s_barrier();
      asm volatile("" ::: "memory");
      const char* lAb = (const char*)(&lds[0] + (kt & 1) * 16384);
      const char* lBb = lAb + 16384;
#pragma unroll
      for (int kk = 0; kk < 2; ++kk) {
        const int kb = kk * 64 + ((l >> 4) * 16);
        short8 af[4], bf[4];
#pragma unroll
        for (int mf = 0; mf < 4; ++mf) {
          int row = wr * 64 + mf * 16 + (l & 15);
          af[mf] = *(const short8*)(lAb + row * 128 + (kb ^ ((row & 7) << 4)));
        }
#pragma unroll
        for (int nf = 0; nf < 4; ++nf) {
          int n = wc * 64 + nf * 16 + (l & 15);
          bf[nf] = *(const short8*)(lBb + n * 128 + (kb ^ ((n & 7) << 4)));
        }
        __builtin_amdgcn_s_setprio(1);
#pragma unroll
        for (int mf = 0; mf < 4; ++mf)
#pragma unroll
          for (int nf = 0; nf < 4; ++nf)
            acc[mf][nf] = __builtin_amdgcn_mfma_f32_16x16x32_bf16(af[mf], bf[nf], acc[mf][nf], 0, 0, 0);
        __builtin_amdgcn_s_setprio(0);
      }
      asm volatile("" ::: "memory");
      __builtin_amdgcn_s_barrier();
      asm volatile("" ::: "memory");
    }
  }

  const int g4 = (l >> 4) * 4;
  const int cL = l & 15;
  const int colb = cb2 * 128 + wc * 64;

  if constexpr (MODE == 0 || MODE == 2) {
    unsigned short* Out = (cb < nsplit) ? O0 : O1;
    const int obase = (MODE == 0) ? offsets[e] : 0;
#pragma unroll
    for (int mf = 0; mf < 4; ++mf)
#pragma unroll
      for (int r = 0; r < 4; ++r) {
        int rloc = rb * 128 + wr * 64 + mf * 16 + g4 + r;
        if (MODE == 0 && rloc >= cnt) continue;
        size_t orow = (size_t)(obase + rloc) * ldo + colb;
#pragma unroll
        for (int nf = 0; nf < 4; ++nf)
          Out[orow + nf * 16 + cL] = f2bf(acc[mf][nf][r]);
      }
  } else if constexpr (MODE == 1) {
#pragma unroll
    for (int mf = 0; mf < 4; ++mf)
#pragma unroll
      for (int r = 0; r < 4; ++r) {
        int rloc = rb * 128 + wr * 64 + mf * 16 + g4 + r;
        if (rloc < cnt) {
          int tok = list[e * T_TOK + rloc];
          float* dst = OF + (size_t)tok * HD + colb;
#pragma unroll
          for (int nf = 0; nf < 4; ++nf)
            atomicAdd(dst + nf * 16 + cL, acc[mf][nf][r]);
        }
      }
  } else {
#pragma unroll
    for (int mf = 0; mf < 4; ++mf)
#pragma unroll
      for (int r = 0; r < 4; ++r) {
        int t = rb * 128 + wr * 64 + mf * 16 + g4 + r;
        float g = gate_sh[t];
        float* dst = OF + (size_t)t * HD + colb;
#pragma unroll
        for (int nf = 0; nf < 4; ++nf)
          dst[nf * 16 + cL] = g * acc[mf][nf][r];   // pure write, initializes out
      }
  }
}

// ---------------- fused SiLU(g)*u*(weight) elementwise, in place into u --------
__global__ __launch_bounds__(256) void k_silu(
    const unsigned short* __restrict__ gq, unsigned short* __restrict__ uq,
    const float* __restrict__ wrow, long total)
{
  long i = ((long)blockIdx.x * blockDim.x + threadIdx.x) * 4;
  const long stride = (long)gridDim.x * blockDim.x * 4;
  for (; i < total; i += stride) {
    ushort4 gv = *(const ushort4*)(gq + i);
    ushort4 uv = *(const ushort4*)(uq + i);
    float w = wrow ? wrow[i >> 10] : 1.f;
    float a0 = bf2f(gv.x), a1 = bf2f(gv.y), a2 = bf2f(gv.z), a3 = bf2f(gv.w);
    float b0 = bf2f(uv.x), b1 = bf2f(uv.y), b2 = bf2f(uv.z), b3 = bf2f(uv.w);
    ushort4 o;
    o.x = f2bf(a0 / (1.f + __expf(-a0)) * b0 * w);
    o.y = f2bf(a1 / (1.f + __expf(-a1)) * b1 * w);
    o.z = f2bf(a2 / (1.f + __expf(-a2)) * b2 * w);
    o.w = f2bf(a3 / (1.f + __expf(-a3)) * b3 * w);
    *(ushort4*)(uq + i) = o;
  }
}

extern "C" void kernel_launch(void* const* d_in, const int* in_sizes, int n_in,
                              void* d_out, int out_size, void* d_ws, size_t ws_size,
                              hipStream_t stream) {
  const float* x     = (const float*)d_in[0];
  const float* wrout = (const float*)d_in[1];
  const float* wgate = (const float*)d_in[2];
  const float* wup   = (const float*)d_in[3];
  const float* wdown = (const float*)d_in[4];
  const float* wsg   = (const float*)d_in[5];
  const float* wsu   = (const float*)d_in[6];
  const float* wsd   = (const float*)d_in[7];
  const float* wseg  = (const float*)d_in[8];
  float* out = (float*)d_out;

  char* ws = (char*)d_ws;
  unsigned short* xb = (unsigned short*)ws;                         // 8 MB
  char* region1 = ws + (size_t)(8u << 20);                          // 46 MB acts
  unsigned short* sgg  = (unsigned short*)region1;                  // shared g: 22 MB
  unsigned short* sgu  = (unsigned short*)(region1 + (size_t)23068672);
  unsigned short* actg = (unsigned short*)region1;                  // expert g (reuse)
  unsigned short* actu = (unsigned short*)(region1 + (size_t)(16u << 20));
  char* p3 = region1 + (size_t)46137344;                            // meta 1 MB
  int*   counts  = (int*)p3;
  int*   offsets = (int*)(p3 + 256);
  float* gateS   = (float*)(p3 + 512);
  float* wpair   = (float*)(p3 + 512 + 8192);
  int*   list    = (int*)(p3 + 512 + 8192 + 32768);
  int*   tk_ids  = (int*)(p3 + 512 + 8192 + 32768 + 131072);
  float* tk_w    = (float*)(p3 + 512 + 8192 + 32768 + 131072 + 32768);
  char* p4 = p3 + (size_t)(1u << 20);
  unsigned short* W1 = (unsigned short*)p4;                         // 64 MB
  (void)ws_size; (void)in_sizes; (void)n_in; (void)out_size;

  const int n = T_TOK * HD;
  k_prep<<<dim3(2048), dim3(256), 0, stream>>>(x, xb, n);
  k_router2<<<dim3(T_TOK / 4), dim3(256), 0, stream>>>(x, wrout, wseg, tk_ids, tk_w, gateS);
  k_offsets2<<<dim3(1), dim3(256), 0, stream>>>(tk_ids, counts, offsets);
  k_build<<<dim3(NE), dim3(256), 0, stream>>>(tk_ids, tk_w, offsets, list, wpair);

  // ---- shared path first (its down-proj initializes out with a pure write) ----
  // shared g+u combined, fp32 B direct (no transpose pass)
  k_gemm<2><<<dim3(88, 16, 1), dim3(256), 0, stream>>>(
      xb, HD, HD, (const unsigned short*)nullptr, (const unsigned short*)nullptr,
      wsg, wsu, SHF, 44, (size_t)0,
      sgg, sgu, SHF, (float*)nullptr, counts, offsets, list, (const float*)nullptr);
  k_silu<<<dim3(4096), dim3(256), 0, stream>>>(sgg, sgu, (const float*)nullptr, (long)T_TOK * SHF);

  // transpose w_sh_down -> W1: [2048 n][5632 k]
  k_transpose<<<dim3(88, 32, 1), dim3(256), 0, stream>>>(wsd, W1, SHF, HD);
  // shared down (dbuf core): out[t] = gate[t] * (act_s @ w_sh_down)
  k_gemm<3><<<dim3(16, 16, 1), dim3(256), 0, stream>>>(
      sgu, SHF, SHF, W1, W1,
      (const float*)nullptr, (const float*)nullptr, 0, 1 << 30, (size_t)0,
      (unsigned short*)nullptr, (unsigned short*)nullptr, HD,
      out, counts, offsets, list, gateS);

  // ---- expert path (atomicAdd on top of initialized out) ----------------------
  // expert g+u combined, fp32 B direct (no transpose passes)
  k_gemm<0><<<dim3(16, 16, 16), dim3(256), 0, stream>>>(
      xb, HD, HD, (const unsigned short*)nullptr, (const unsigned short*)nullptr,
      wgate, wup, FF, 8, (size_t)HD * FF,
      actg, actu, FF, (float*)nullptr, counts, offsets, list, (const float*)nullptr);
  k_silu<<<dim3(4096), dim3(256), 0, stream>>>(actg, actu, wpair, (long)T_TOK * TOPK * FF);

  // transpose w_down -> W1: [16][2048 n][1024 k]
  k_transpose<<<dim3(16, 32, 16), dim3(256), 0, stream>>>(wdown, W1, FF, HD);
  // expert down (dbuf core): out[tok] += act_e @ w_down[e]  (atomic f32)
  k_gemm<1><<<dim3(16, 16, 16), dim3(256), 0, stream>>>(
      actu, FF, FF, W1, W1,
      (const float*)nullptr, (const float*)nullptr, 0, 1 << 30, (size_t)FF * HD,
      (unsigned short*)nullptr, (unsigned short*)nullptr, HD,
      out, counts, offsets, list, (const float*)nullptr);
}

// Round 13
// 584.756 us; speedup vs baseline: 1.0476x; 1.0476x over previous
//
#include <hip/hip_runtime.h>
#include <hip/hip_bf16.h>
#include <stdint.h>

#define T_TOK 2048
#define HD    2048
#define NE    16
#define FF    1024
#define TOPK  4
#define SHF   5632

typedef __attribute__((ext_vector_type(8))) short short8;
typedef __attribute__((ext_vector_type(4))) float f32x4;

typedef const __attribute__((address_space(1))) uint32_t* gp1_t;
typedef __attribute__((address_space(3))) uint32_t* lp3_t;

__device__ __forceinline__ void gload_lds16(const void* g, void* l) {
  __builtin_amdgcn_global_load_lds((gp1_t)g, (lp3_t)l, 16, 0, 0);
}

__device__ __forceinline__ unsigned short f2bf(float f) {
  __hip_bfloat16 h = __float2bfloat16(f);
  return __builtin_bit_cast(unsigned short, h);
}
__device__ __forceinline__ float bf2f(unsigned short u) {
  return __uint_as_float(((uint32_t)u) << 16);
}

// ---------------- weight transpose+cast: [b][K][N] fp32 -> [b][N][K] bf16 ------
__global__ __launch_bounds__(256) void k_transpose(const float* __restrict__ src,
    unsigned short* __restrict__ dst, int K, int N) {
  __shared__ unsigned short tile[64][72];
  const int k0 = blockIdx.x * 64;
  const int n0 = blockIdx.y * 64;
  const size_t boff = (size_t)blockIdx.z * K * N;
  src += boff; dst += boff;
  const int t = threadIdx.x;
  const int c4 = (t & 15) * 4;
  const int kr0 = (t >> 4) * 4;
#pragma unroll
  for (int j = 0; j < 4; ++j) {
    int kr = kr0 + j;
    float4 v = *(const float4*)(src + (size_t)(k0 + kr) * N + n0 + c4);
    tile[c4 + 0][kr] = f2bf(v.x);
    tile[c4 + 1][kr] = f2bf(v.y);
    tile[c4 + 2][kr] = f2bf(v.z);
    tile[c4 + 3][kr] = f2bf(v.w);
  }
  __syncthreads();
  const int nr = t >> 2;
  const int kc = (t & 3) * 8;
  unsigned short* orow = dst + (size_t)(n0 + nr) * K + k0;
  *(short8*)(orow + kc)      = *(const short8*)(&tile[nr][kc]);
  *(short8*)(orow + kc + 32) = *(const short8*)(&tile[nr][kc + 32]);
}

// ---------------- paired transpose (two tensors, one launch; z-partitioned) ----
__global__ __launch_bounds__(256) void k_transpose2(
    const float* __restrict__ s0, const float* __restrict__ s1,
    unsigned short* __restrict__ d0, unsigned short* __restrict__ d1,
    int K, int N, int nz0) {
  __shared__ unsigned short tile[64][72];
  const int k0 = blockIdx.x * 64;
  const int n0 = blockIdx.y * 64;
  const int z = blockIdx.z;
  const float* src = (z < nz0) ? s0 : s1;
  unsigned short* dst = (z < nz0) ? d0 : d1;
  const int zb = (z < nz0) ? z : z - nz0;
  const size_t boff = (size_t)zb * K * N;
  src += boff; dst += boff;
  const int t = threadIdx.x;
  const int c4 = (t & 15) * 4;
  const int kr0 = (t >> 4) * 4;
#pragma unroll
  for (int j = 0; j < 4; ++j) {
    int kr = kr0 + j;
    float4 v = *(const float4*)(src + (size_t)(k0 + kr) * N + n0 + c4);
    tile[c4 + 0][kr] = f2bf(v.x);
    tile[c4 + 1][kr] = f2bf(v.y);
    tile[c4 + 2][kr] = f2bf(v.z);
    tile[c4 + 3][kr] = f2bf(v.w);
  }
  __syncthreads();
  const int nr = t >> 2;
  const int kc = (t & 3) * 8;
  unsigned short* orow = dst + (size_t)(n0 + nr) * K + k0;
  *(short8*)(orow + kc)      = *(const short8*)(&tile[nr][kc]);
  *(short8*)(orow + kc + 32) = *(const short8*)(&tile[nr][kc + 32]);
}

// ---------------- router: wave = token, float4 loads, NO atomics; also emits
// xb (x cast to bf16) from the same registers -- replaces k_prep ---------------
__global__ __launch_bounds__(256) void k_router2(
    const float* __restrict__ x, const float* __restrict__ wr,
    const float* __restrict__ wsg, unsigned short* __restrict__ xb,
    int* __restrict__ tk_ids, float* __restrict__ tk_w,
    float* __restrict__ gate_sh) {
  const int t = blockIdx.x * 4 + (threadIdx.x >> 6);
  const int lane = threadIdx.x & 63;
  const float4* x4  = (const float4*)(x + (size_t)t * HD);
  const float4* wg4 = (const float4*)wsg;
  unsigned short* xbrow = xb + (size_t)t * HD;
  float p[NE + 1];
#pragma unroll
  for (int e = 0; e <= NE; ++e) p[e] = 0.f;
#pragma unroll
  for (int j = 0; j < 8; ++j) {
    const int i4 = lane + 64 * j;
    float4 xv = x4[i4];
    ushort4 xo;
    xo.x = f2bf(xv.x); xo.y = f2bf(xv.y); xo.z = f2bf(xv.z); xo.w = f2bf(xv.w);
    *(ushort4*)(xbrow + i4 * 4) = xo;
    const float4* wrow = (const float4*)(wr + (size_t)i4 * 4 * NE);
#pragma unroll
    for (int r = 0; r < 4; ++r) {
      float xs = (&xv.x)[r];
#pragma unroll
      for (int c = 0; c < 4; ++c) {
        float4 wv = wrow[r * 4 + c];
        p[c * 4 + 0] += xs * wv.x;
        p[c * 4 + 1] += xs * wv.y;
        p[c * 4 + 2] += xs * wv.z;
        p[c * 4 + 3] += xs * wv.w;
      }
    }
    float4 gv = wg4[i4];
    p[NE] += xv.x * gv.x + xv.y * gv.y + xv.z * gv.z + xv.w * gv.w;
  }
#pragma unroll
  for (int e = 0; e <= NE; ++e) {
    float v = p[e];
    for (int off = 32; off; off >>= 1) v += __shfl_xor(v, off);
    p[e] = v;
  }
  if (lane == 0) {
    gate_sh[t] = 1.f / (1.f + __expf(-p[NE]));
    float l[NE];
#pragma unroll
    for (int e = 0; e < NE; ++e) l[e] = p[e];
    int ids[TOPK]; float lg[TOPK];
#pragma unroll
    for (int k = 0; k < TOPK; ++k) {
      int best = 0; float bv = l[0];
#pragma unroll
      for (int e = 1; e < NE; ++e) { if (l[e] > bv) { bv = l[e]; best = e; } }
      ids[k] = best; lg[k] = bv; l[best] = -1e30f;
    }
    float m = lg[0], s = 0.f, w[TOPK];
#pragma unroll
    for (int k = 0; k < TOPK; ++k) { w[k] = __expf(lg[k] - m); s += w[k]; }
    float inv = 1.f / s;
#pragma unroll
    for (int k = 0; k < TOPK; ++k) {
      tk_ids[t * TOPK + k] = ids[k];
      tk_w[t * TOPK + k] = w[k] * inv;
    }
  }
}

// ---------------- counts + offsets via LDS histogram (1 block) -----------------
__global__ __launch_bounds__(256) void k_offsets2(
    const int* __restrict__ tk_ids, int* __restrict__ counts,
    int* __restrict__ offsets) {
  __shared__ int h[NE];
  const int tid = threadIdx.x;
  if (tid < NE) h[tid] = 0;
  __syncthreads();
  for (int i = tid; i < T_TOK * TOPK; i += 256) atomicAdd(&h[tk_ids[i]], 1);
  __syncthreads();
  if (tid == 0) {
    int off = 0;
    for (int e = 0; e < NE; ++e) { counts[e] = h[e]; offsets[e] = off; off += h[e]; }
    offsets[NE] = off;
  }
}

// ---------------- per-expert list build: ballot prefix, token-ordered ----------
__global__ __launch_bounds__(256) void k_build(
    const int* __restrict__ tk_ids, const float* __restrict__ tk_w,
    const int* __restrict__ offsets, int* __restrict__ list,
    float* __restrict__ wpair) {
  const int e = blockIdx.x;
  const int tid = threadIdx.x, lane = tid & 63, w = tid >> 6;
  __shared__ int wbase[4];
  __shared__ int sbase;
  if (tid == 0) sbase = 0;
  __syncthreads();
  const int obase = offsets[e];
  for (int c = 0; c < T_TOK / 256; ++c) {
    int t = c * 256 + tid;
    int m = -1;
#pragma unroll
    for (int k = 0; k < TOPK; ++k)
      if (tk_ids[t * TOPK + k] == e) m = k;
    unsigned long long mask = __ballot(m >= 0);
    int posw = __popcll(mask & ((1ull << lane) - 1ull));
    if (lane == 0) wbase[w] = __popcll(mask);
    __syncthreads();
    int wb = 0;
#pragma unroll
    for (int j = 0; j < 4; ++j) if (j < w) wb += wbase[j];
    int tot = wbase[0] + wbase[1] + wbase[2] + wbase[3];
    if (m >= 0) {
      int pos = sbase + wb + posw;
      list[e * T_TOK + pos] = t;
      wpair[obase + pos] = tk_w[t * TOPK + m];
    }
    __syncthreads();
    if (tid == 0) sbase += tot;
    __syncthreads();
  }
}

// ---------------- 128x128x64 bf16 MFMA GEMM, mixed-core (R11-proven) ----------
// MODE 0/2 (combined g+u, K=2048): sync core, 33 KB LDS, 4 blocks/CU; dual-B
//   panels via nsplit (cb < nsplit -> B0/O0, else B1/O1).
// MODE 1/3 (down projections): dbuf 2-phase core, 66 KB LDS, counted vmcnt(8).
// MODE 0: expert rows gathered by list (compact out); MODE 1: expert down ->
// atomicAdd OF[token]; MODE 2: shared direct; MODE 3: shared down -> pure write
// OF[t] = gate_sh[t]*acc (initializes out; runs before expert-down atomics).
template<int MODE>
__global__ __launch_bounds__(256) void k_gemm(
    const unsigned short* __restrict__ A, int lda, int K,
    const unsigned short* __restrict__ B0, const unsigned short* __restrict__ B1,
    int nsplit, size_t strideB,
    unsigned short* __restrict__ O0, unsigned short* __restrict__ O1, int ldo,
    float* __restrict__ OF,
    const int* __restrict__ counts, const int* __restrict__ offsets,
    const int* __restrict__ list, const float* __restrict__ gate_sh)
{
  constexpr bool DBUF = (MODE == 1 || MODE == 3);
  __shared__ unsigned short lds[DBUF ? 2 * 16384 : 16384];
  __shared__ int tokLDS[128];

  const int cb = blockIdx.x, rb = blockIdx.y;
  const int e = (MODE <= 1) ? blockIdx.z : 0;
  const int tid = threadIdx.x, l = tid & 63, wid = tid >> 6;
  const int wr = wid >> 1, wc = wid & 1;

  int cnt = T_TOK;
  if (MODE <= 1) {
    cnt = counts[e];
    if (rb * 128 >= cnt) return;
  }
  if (MODE == 0) {
    if (tid < 128) {
      int r = rb * 128 + tid;
      tokLDS[tid] = list[e * T_TOK + (r < cnt ? r : cnt - 1)];
    }
    __syncthreads();
  }

  const int swz8 = ((l & 7) ^ (l >> 3)) * 8;
  const unsigned short* Bsel = (cb < nsplit) ? B0 : B1;
  const int cb2 = (cb < nsplit) ? cb : cb - nsplit;
  const size_t eoff = (MODE <= 1) ? (size_t)e * strideB : (size_t)0;

  const unsigned short* aS[4];
  const unsigned short* bS[4];
#pragma unroll
  for (int i = 0; i < 4; ++i) {
    int rloc = wid * 32 + i * 8 + (l >> 3);
    int arow;
    if (MODE == 0) arow = tokLDS[rloc];
    else if (MODE == 1) { int rr = rb * 128 + rloc; if (rr >= cnt) rr = cnt - 1; arow = offsets[e] + rr; }
    else arow = rb * 128 + rloc;
    aS[i] = A + (size_t)arow * lda + swz8;
    bS[i] = Bsel + eoff + (size_t)(cb2 * 128 + rloc) * K + swz8;
  }

  f32x4 acc[4][4];
#pragma unroll
  for (int mf = 0; mf < 4; ++mf)
#pragma unroll
    for (int nf = 0; nf < 4; ++nf) acc[mf][nf] = (f32x4){0.f, 0.f, 0.f, 0.f};

  const int nkt = K / 64;

  if constexpr (!DBUF) {
    // ---- sync core: 33 KB, 4 blocks/CU, cross-block TLP hides the drain ----
    for (int kt = 0; kt < nkt; ++kt) {
      const int k0 = kt * 64;
      unsigned short* base = &lds[0] + (wid * 32) * 64;
#pragma unroll
      for (int i = 0; i < 4; ++i) {
        gload_lds16(aS[i] + k0, base + i * 8 * 64);
        gload_lds16(bS[i] + k0, base + i * 8 * 64 + 8192);
      }
      __syncthreads();
      const char* lAb = (const char*)&lds[0];
      const char* lBb = lAb + 16384;
#pragma unroll
      for (int kk = 0; kk < 2; ++kk) {
        const int kb = kk * 64 + ((l >> 4) * 16);
        short8 af[4], bf[4];
#pragma unroll
        for (int mf = 0; mf < 4; ++mf) {
          int row = wr * 64 + mf * 16 + (l & 15);
          af[mf] = *(const short8*)(lAb + row * 128 + (kb ^ ((row & 7) << 4)));
        }
#pragma unroll
        for (int nf = 0; nf < 4; ++nf) {
          int n = wc * 64 + nf * 16 + (l & 15);
          bf[nf] = *(const short8*)(lBb + n * 128 + (kb ^ ((n & 7) << 4)));
        }
#pragma unroll
        for (int mf = 0; mf < 4; ++mf)
#pragma unroll
          for (int nf = 0; nf < 4; ++nf)
            acc[mf][nf] = __builtin_amdgcn_mfma_f32_16x16x32_bf16(af[mf], bf[nf], acc[mf][nf], 0, 0, 0);
      }
      __syncthreads();
    }
  } else {
    // ---- dbuf 2-phase core (best for short-K down gemms) ----
    auto STAGE = [&](int kt) {
      unsigned short* base = &lds[0] + (kt & 1) * 16384 + (wid * 32) * 64;
      const int k0 = kt * 64;
#pragma unroll
      for (int i = 0; i < 4; ++i) {
        gload_lds16(aS[i] + k0, base + i * 8 * 64);
        gload_lds16(bS[i] + k0, base + i * 8 * 64 + 8192);
      }
    };
    STAGE(0);
    for (int kt = 0; kt < nkt; ++kt) {
      if (kt + 1 < nkt) {
        STAGE(kt + 1);
        asm volatile("s_waitcnt vmcnt(8)" ::: "memory");
      } else {
        asm volatile("s_waitcnt vmcnt(0)" ::: "memory");
      }
      __builtin_amdgcn_s_barrier();
      asm volatile("" ::: "memory");
      const char* lAb = (const char*)(&lds[0] + (kt & 1) * 16384);
      const char* lBb = lAb + 16384;
#pragma unroll
      for (int kk = 0; kk < 2; ++kk) {
        const int kb = kk * 64 + ((l >> 4) * 16);
        short8 af[4], bf[4];
#pragma unroll
        for (int mf = 0; mf < 4; ++mf) {
          int row = wr * 64 + mf * 16 + (l & 15);
          af[mf] = *(const short8*)(lAb + row * 128 + (kb ^ ((row & 7) << 4)));
        }
#pragma unroll
        for (int nf = 0; nf < 4; ++nf) {
          int n = wc * 64 + nf * 16 + (l & 15);
          bf[nf] = *(const short8*)(lBb + n * 128 + (kb ^ ((n & 7) << 4)));
        }
        __builtin_amdgcn_s_setprio(1);
#pragma unroll
        for (int mf = 0; mf < 4; ++mf)
#pragma unroll
          for (int nf = 0; nf < 4; ++nf)
            acc[mf][nf] = __builtin_amdgcn_mfma_f32_16x16x32_bf16(af[mf], bf[nf], acc[mf][nf], 0, 0, 0);
        __builtin_amdgcn_s_setprio(0);
      }
      asm volatile("" ::: "memory");
      __builtin_amdgcn_s_barrier();
      asm volatile("" ::: "memory");
    }
  }

  const int g4 = (l >> 4) * 4;
  const int cL = l & 15;
  const int colb = cb2 * 128 + wc * 64;

  if constexpr (MODE == 0 || MODE == 2) {
    unsigned short* Out = (cb < nsplit) ? O0 : O1;
    const int obase = (MODE == 0) ? offsets[e] : 0;
#pragma unroll
    for (int mf = 0; mf < 4; ++mf)
#pragma unroll
      for (int r = 0; r < 4; ++r) {
        int rloc = rb * 128 + wr * 64 + mf * 16 + g4 + r;
        if (MODE == 0 && rloc >= cnt) continue;
        size_t orow = (size_t)(obase + rloc) * ldo + colb;
#pragma unroll
        for (int nf = 0; nf < 4; ++nf)
          Out[orow + nf * 16 + cL] = f2bf(acc[mf][nf][r]);
      }
  } else if constexpr (MODE == 1) {
#pragma unroll
    for (int mf = 0; mf < 4; ++mf)
#pragma unroll
      for (int r = 0; r < 4; ++r) {
        int rloc = rb * 128 + wr * 64 + mf * 16 + g4 + r;
        if (rloc < cnt) {
          int tok = list[e * T_TOK + rloc];
          float* dst = OF + (size_t)tok * HD + colb;
#pragma unroll
          for (int nf = 0; nf < 4; ++nf)
            atomicAdd(dst + nf * 16 + cL, acc[mf][nf][r]);
        }
      }
  } else {
#pragma unroll
    for (int mf = 0; mf < 4; ++mf)
#pragma unroll
      for (int r = 0; r < 4; ++r) {
        int t = rb * 128 + wr * 64 + mf * 16 + g4 + r;
        float g = gate_sh[t];
        float* dst = OF + (size_t)t * HD + colb;
#pragma unroll
        for (int nf = 0; nf < 4; ++nf)
          dst[nf * 16 + cL] = g * acc[mf][nf][r];   // pure write, initializes out
      }
  }
}

// ---------------- fused SiLU(g)*u*(weight) elementwise, in place into u --------
__global__ __launch_bounds__(256) void k_silu(
    const unsigned short* __restrict__ gq, unsigned short* __restrict__ uq,
    const float* __restrict__ wrow, long total)
{
  long i = ((long)blockIdx.x * blockDim.x + threadIdx.x) * 4;
  const long stride = (long)gridDim.x * blockDim.x * 4;
  for (; i < total; i += stride) {
    ushort4 gv = *(const ushort4*)(gq + i);
    ushort4 uv = *(const ushort4*)(uq + i);
    float w = wrow ? wrow[i >> 10] : 1.f;
    float a0 = bf2f(gv.x), a1 = bf2f(gv.y), a2 = bf2f(gv.z), a3 = bf2f(gv.w);
    float b0 = bf2f(uv.x), b1 = bf2f(uv.y), b2 = bf2f(uv.z), b3 = bf2f(uv.w);
    ushort4 o;
    o.x = f2bf(a0 / (1.f + __expf(-a0)) * b0 * w);
    o.y = f2bf(a1 / (1.f + __expf(-a1)) * b1 * w);
    o.z = f2bf(a2 / (1.f + __expf(-a2)) * b2 * w);
    o.w = f2bf(a3 / (1.f + __expf(-a3)) * b3 * w);
    *(ushort4*)(uq + i) = o;
  }
}

extern "C" void kernel_launch(void* const* d_in, const int* in_sizes, int n_in,
                              void* d_out, int out_size, void* d_ws, size_t ws_size,
                              hipStream_t stream) {
  const float* x     = (const float*)d_in[0];
  const float* wrout = (const float*)d_in[1];
  const float* wgate = (const float*)d_in[2];
  const float* wup   = (const float*)d_in[3];
  const float* wdown = (const float*)d_in[4];
  const float* wsg   = (const float*)d_in[5];
  const float* wsu   = (const float*)d_in[6];
  const float* wsd   = (const float*)d_in[7];
  const float* wseg  = (const float*)d_in[8];
  float* out = (float*)d_out;

  char* ws = (char*)d_ws;
  unsigned short* xb = (unsigned short*)ws;                         // 8 MB
  char* region1 = ws + (size_t)(8u << 20);                          // 46 MB acts
  unsigned short* sgg  = (unsigned short*)region1;                  // shared g: 22 MB
  unsigned short* sgu  = (unsigned short*)(region1 + (size_t)23068672);
  unsigned short* actg = (unsigned short*)region1;                  // expert g (reuse)
  unsigned short* actu = (unsigned short*)(region1 + (size_t)(16u << 20));
  char* p3 = region1 + (size_t)46137344;                            // meta 1 MB
  int*   counts  = (int*)p3;
  int*   offsets = (int*)(p3 + 256);
  float* gateS   = (float*)(p3 + 512);
  float* wpair   = (float*)(p3 + 512 + 8192);
  int*   list    = (int*)(p3 + 512 + 8192 + 32768);
  int*   tk_ids  = (int*)(p3 + 512 + 8192 + 32768 + 131072);
  float* tk_w    = (float*)(p3 + 512 + 8192 + 32768 + 131072 + 32768);
  char* p4 = p3 + (size_t)(1u << 20);
  unsigned short* W1 = (unsigned short*)p4;                         // 64 MB
  unsigned short* W2 = (unsigned short*)(p4 + (size_t)(64u << 20)); // 64 MB
  (void)ws_size; (void)in_sizes; (void)n_in; (void)out_size;

  // router (also emits xb = bf16(x)), offsets, per-expert lists — no atomics
  k_router2<<<dim3(T_TOK / 4), dim3(256), 0, stream>>>(x, wrout, wseg, xb, tk_ids, tk_w, gateS);
  k_offsets2<<<dim3(1), dim3(256), 0, stream>>>(tk_ids, counts, offsets);
  k_build<<<dim3(NE), dim3(256), 0, stream>>>(tk_ids, tk_w, offsets, list, wpair);

  // ---- shared path first (its down-proj initializes out with a pure write) ----
  unsigned short* WsgT = W2;                        // 5632 x 2048 bf16
  unsigned short* WsuT = W2 + (size_t)SHF * HD;
  k_transpose2<<<dim3(32, 88, 2), dim3(256), 0, stream>>>(
      wsg, wsu, WsgT, WsuT, HD, SHF, 1);

  // shared g+u combined (one dispatch, dual-B): sgg/sgu [2048,5632] bf16
  k_gemm<2><<<dim3(88, 16, 1), dim3(256), 0, stream>>>(
      xb, HD, HD, WsgT, WsuT, 44, (size_t)0,
      sgg, sgu, SHF, (float*)nullptr, counts, offsets, list, (const float*)nullptr);
  k_silu<<<dim3(4096), dim3(256), 0, stream>>>(sgg, sgu, (const float*)nullptr, (long)T_TOK * SHF);

  // transpose w_sh_down -> W1: [2048 n][5632 k]
  k_transpose<<<dim3(88, 32, 1), dim3(256), 0, stream>>>(wsd, W1, SHF, HD);
  // shared down (dbuf core): out[t] = gate[t] * (act_s @ w_sh_down)
  k_gemm<3><<<dim3(16, 16, 1), dim3(256), 0, stream>>>(
      sgu, SHF, SHF, W1, W1, 1 << 30, (size_t)0,
      (unsigned short*)nullptr, (unsigned short*)nullptr, HD,
      out, counts, offsets, list, gateS);

  // ---- expert path (atomicAdd on top of initialized out) ----------------------
  k_transpose2<<<dim3(32, 16, 32), dim3(256), 0, stream>>>(
      wgate, wup, W1, W2, HD, FF, 16);

  // expert g+u combined (one dispatch, dual-B): actg/actu [pairs,1024] bf16
  k_gemm<0><<<dim3(16, 16, 16), dim3(256), 0, stream>>>(
      xb, HD, HD, W1, W2, 8, (size_t)HD * FF,
      actg, actu, FF, (float*)nullptr, counts, offsets, list, (const float*)nullptr);
  k_silu<<<dim3(4096), dim3(256), 0, stream>>>(actg, actu, wpair, (long)T_TOK * TOPK * FF);

  // transpose w_down -> W1: [16][2048 n][1024 k]
  k_transpose<<<dim3(16, 32, 16), dim3(256), 0, stream>>>(wdown, W1, FF, HD);
  // expert down (dbuf core): out[tok] += act_e @ w_down[e]  (atomic f32)
  k_gemm<1><<<dim3(16, 16, 16), dim3(256), 0, stream>>>(
      actu, FF, FF, W1, W1, 1 << 30, (size_t)FF * HD,
      (unsigned short*)nullptr, (unsigned short*)nullptr, HD,
      out, counts, offsets, list, (const float*)nullptr);
}